// Round 5
// baseline (159.922 us; speedup 1.0000x reference)
//
#include <hip/hip_runtime.h>

// Batched 3D affine spatial transformer: vol [B=4,160,192,160,1] fp32, trf [4,4,4] fp32.
// R9: R7/R8 showed occupancy pushes are exhausted (6->8 blk/CU bought 1us; all pipes
// <=50%). The wall is the per-block one-shot {stage -> vmcnt(0) drain -> compute}
// lifecycle: ~700cy of fully-exposed barrier drain per wave. Fix = T3/T4 pipeline:
// each block does NC=4 d-chunks with double-buffered LDS; stage(c+1) issues 30 loads,
// then s_waitcnt vmcnt(34) (30 new loads + 4 stores stay in flight; FIFO retire =>
// chunk c's loads are done) + raw s_barrier. Staging hides under compute. Staging is
// FIXED at 30 load-instructions/wave/chunk (loop to caps, clamped source rows) so the
// vmcnt literal is exact on every path. No __syncthreads anywhere (it would inject
// vmcnt(0) drains). LDS 2x19.2KB -> 4 blk/CU; launch_bounds(256,4) caps VGPR at 128
// so no scratch ops can pollute the vmcnt FIFO.
constexpr int D = 160, H = 192, W = 160, B = 4;
constexpr int V  = D * H * W;
constexpr int HW = H * W;
constexpr int VPT = 4;                 // output voxels per chunk along d
constexpr int NC  = 4;                 // chunks per block (pipelined)
constexpr int TW  = 32, TH = 8;        // output tile in (w,h); block = (32,8)
constexpr int GXW = W / TW;            // 5
constexpr int GXH = H / TH;            // 24
constexpr int SD_CAP = 10, SH_CAP = 12, SW_CAP = 40;
constexpr int PLANE = SH_CAP * SW_CAP;             // 480 floats
constexpr int CHUNK_FLOATS = SD_CAP * PLANE;       // 4800 floats = 19200 B
// Staging: SD_CAP z-planes x 3 y-rows per wave = 30 global_load_lds per wave, always.
constexpr int STAGE_LOADS = SD_CAP * 3;            // 30
constexpr int STORES_PER_CHUNK = VPT;              // 4

struct DimS { int i0; float w0; };

// Equivalent to neuron.utils interpn clipping (verified R3):
//   c = clip(loc,0,max); i0 = min((int)c, maxi-1); i1 = i0+1; w0 = (i0+1) - c.
__device__ __forceinline__ DimS prep(float loc, float maxv, int maxi) {
    float c  = __builtin_amdgcn_fmed3f(loc, 0.0f, maxv);   // clamp, 1 VALU
    int  i0  = min((int)c, maxi - 1);
    DimS s;
    s.i0 = i0;
    s.w0 = (float)(i0 + 1) - c;
    return s;
}

__device__ __forceinline__ float lerp3(DimS sd, DimS sh, DimS sw,
                                       float2 v00, float2 v01,
                                       float2 v10, float2 v11) {
    const float pd00 = fmaf(sw.w0, v00.x - v00.y, v00.y);
    const float pd01 = fmaf(sw.w0, v01.x - v01.y, v01.y);
    const float pd10 = fmaf(sw.w0, v10.x - v10.y, v10.y);
    const float pd11 = fmaf(sw.w0, v11.x - v11.y, v11.y);
    const float q0 = fmaf(sh.w0, pd00 - pd01, pd01);
    const float q1 = fmaf(sh.w0, pd10 - pd11, pd11);
    return fmaf(sd.w0, q0 - q1, q1);
}

__device__ __forceinline__ float trilerp_g(const float* __restrict__ vb,
                                           DimS sd, DimS sh, DimS sw) {
    const float* p0 = vb + ((sd.i0 * H + sh.i0) * W + sw.i0);
    float2 v00, v01, v10, v11;
    __builtin_memcpy(&v00, p0,          8);
    __builtin_memcpy(&v01, p0 + W,      8);
    __builtin_memcpy(&v10, p0 + HW,     8);
    __builtin_memcpy(&v11, p0 + HW + W, 8);
    return lerp3(sd, sh, sw, v00, v01, v10, v11);
}

// Async global->LDS, 4B/lane. LDS dest is wave-uniform base + lane*4 (HW rule);
// inactive lanes neither load nor write. One vmcnt event per instruction.
__device__ __forceinline__ void gload_lds_row(const float* g, float* l) {
    __builtin_amdgcn_global_load_lds(
        (const __attribute__((address_space(1))) void*)g,
        (__attribute__((address_space(3))) void*)l,
        4, 0, 0);
}

__global__ __launch_bounds__(256, 4) void st_affine_kernel(
        const float* __restrict__ vol, const float* __restrict__ trf,
        float* __restrict__ out) {
    __shared__ float sm[2][CHUNK_FLOATS];

    const int b  = blockIdx.z;
    const int dbase = blockIdx.y * (VPT * NC);     // 16 d-voxels per block
    const int hblk = blockIdx.x / GXW;
    const int wblk = blockIdx.x - hblk * GXW;
    const int w0 = wblk * TW, h0 = hblk * TH;

    const float* __restrict__ A = trf + b * 16;    // wave-uniform -> scalar loads
    const float a00 = A[0], a01 = A[1], a02 = A[2],  a03 = A[3];
    const float a10 = A[4], a11 = A[5], a12 = A[6],  a13 = A[7];
    const float a20 = A[8], a21 = A[9], a22 = A[10], a23 = A[11];

    constexpr float cd = (D - 1) * 0.5f;
    constexpr float ch = (H - 1) * 0.5f;
    constexpr float cw = (W - 1) * 0.5f;

    // ---- input coords at the block origin voxel (dbase,h0,w0) ----
    const float md0 = (float)dbase - cd, mh0 = (float)h0 - ch, mw0 = (float)w0 - cw;
    const float od = cd + fmaf(a00, md0, fmaf(a01, mh0, fmaf(a02, mw0, a03)));
    const float oh = ch + fmaf(a10, md0, fmaf(a11, mh0, fmaf(a12, mw0, a13)));
    const float ow = cw + fmaf(a20, md0, fmaf(a21, mh0, fmaf(a22, mw0, a23)));

    // ---- chunk-invariant bbox span offsets (extremes at chunk corners) ----
    const float Ed = (float)(VPT - 1), Eh = (float)(TH - 1), Ew = (float)(TW - 1);
    const float dn_off = fminf(a00*Ed,0.f) + fminf(a01*Eh,0.f) + fminf(a02*Ew,0.f);
    const float dx_off = fmaxf(a00*Ed,0.f) + fmaxf(a01*Eh,0.f) + fmaxf(a02*Ew,0.f);
    const float hn_off = fminf(a10*Ed,0.f) + fminf(a11*Eh,0.f) + fminf(a12*Ew,0.f);
    const float hx_off = fmaxf(a10*Ed,0.f) + fmaxf(a11*Eh,0.f) + fmaxf(a12*Ew,0.f);
    const float wn_off = fminf(a20*Ed,0.f) + fminf(a21*Eh,0.f) + fminf(a22*Ew,0.f);
    const float wx_off = fmaxf(a20*Ed,0.f) + fmaxf(a21*Eh,0.f) + fmaxf(a22*Ew,0.f);

    const int tid  = threadIdx.y * TW + threadIdx.x;
    const int wv   = tid >> 6;                     // wave id 0..3
    const int lane = tid & 63;
    const float* __restrict__ vb = vol + (size_t)b * V;

    // lo = min i0 over chunk, hi = max i1 over chunk ((int)clip monotone in loc).
    auto mkinfo = [&](float odc, float ohc, float owc,
                      int& lod, int& loh, int& low, bool& fit,
                      int& SDc, int& SHc, int& SWc) {
        const int ld_ = min((int)__builtin_amdgcn_fmed3f(odc + dn_off, 0.f, (float)(D-1)), D-2);
        const int hd_ = min((int)__builtin_amdgcn_fmed3f(odc + dx_off, 0.f, (float)(D-1)), D-2) + 1;
        const int lh_ = min((int)__builtin_amdgcn_fmed3f(ohc + hn_off, 0.f, (float)(H-1)), H-2);
        const int hh_ = min((int)__builtin_amdgcn_fmed3f(ohc + hx_off, 0.f, (float)(H-1)), H-2) + 1;
        const int lw_ = min((int)__builtin_amdgcn_fmed3f(owc + wn_off, 0.f, (float)(W-1)), W-2);
        const int hw_ = min((int)__builtin_amdgcn_fmed3f(owc + wx_off, 0.f, (float)(W-1)), W-2) + 1;
        const int SDn = hd_ - ld_ + 1, SHn = hh_ - lh_ + 1, SWn = hw_ - lw_ + 1;
        fit = (SDn <= SD_CAP) && (SHn <= SH_CAP) && (SWn <= SW_CAP);
        SDc = min(SDn, SD_CAP); SHc = min(SHn, SH_CAP); SWc = min(SWn, SW_CAP);
        lod = ld_; loh = lh_; low = lw_;
    };

    // Exactly STAGE_LOADS(30) load instructions per wave, every call: loop to caps,
    // clamp source rows into the real slab; clamped dups land in unused LDS slots.
    auto stage = [&](float* lbuf, int lod, int loh, int low,
                     int SDc, int SHc, int SWc) {
        const bool act = lane < SWc;               // SWc >= 2 -> exec never 0
        const float* gz = vb + (size_t)lod * HW + (size_t)loh * W + low;
#pragma unroll
        for (int z = 0; z < SD_CAP; ++z) {
            const float* gp = gz + (size_t)min(z, SDc - 1) * HW;
            float* lp = lbuf + z * PLANE;
#pragma unroll
            for (int t = 0; t < 3; ++t) {
                const int y  = wv + t * 4;         // 0..11
                const int ys = min(y, SHc - 1);
                if (act) gload_lds_row(gp + (size_t)ys * W + lane, lp + y * SW_CAP);
            }
        }
    };

    // ---- prologue: stage chunk 0, full drain once per block ----
    int lo_d[2], lo_h[2], lo_w[2];
    bool fits[2];
    float odc = od, ohc = oh, owc = ow;            // chunk-origin coords (block-uniform)
    const float st_d = VPT * a00, st_h = VPT * a10, st_w = VPT * a20;
    {
        int SDc, SHc, SWc;
        mkinfo(odc, ohc, owc, lo_d[0], lo_h[0], lo_w[0], fits[0], SDc, SHc, SWc);
        stage(sm[0], lo_d[0], lo_h[0], lo_w[0], SDc, SHc, SWc);
    }
    __builtin_amdgcn_sched_barrier(0);
    asm volatile("s_waitcnt vmcnt(0)" ::: "memory");
    __builtin_amdgcn_s_barrier();
    __builtin_amdgcn_sched_barrier(0);

    // ---- per-thread running sample coords (advance by col0(A) per output voxel) ----
    const float fy = (float)threadIdx.y, fx = (float)threadIdx.x;
    float ld = fmaf(a01, fy, fmaf(a02, fx, od));
    float lh = fmaf(a11, fy, fmaf(a12, fx, oh));
    float lw = fmaf(a21, fy, fmaf(a22, fx, ow));

    float* obk = out + (size_t)b * V + (size_t)dbase * HW
               + (size_t)(h0 + threadIdx.y) * W + (w0 + threadIdx.x);

#pragma unroll
    for (int c = 0; c < NC; ++c) {
        // ---- issue next chunk's stage (30 loads), then counted wait ----
        if (c + 1 < NC) {
            odc += st_d; ohc += st_h; owc += st_w;
            int SDc, SHc, SWc;
            const int p = (c + 1) & 1;
            mkinfo(odc, ohc, owc, lo_d[p], lo_h[p], lo_w[p], fits[p], SDc, SHc, SWc);
            stage(sm[p], lo_d[p], lo_h[p], lo_w[p], SDc, SHc, SWc);
            __builtin_amdgcn_sched_barrier(0);
            // FIFO: [stage(c):30][stores(c-1):4][stage(c+1):30] -> <=34 left means
            // stage(c) fully retired. Never drain to 0 in the loop (T4).
            asm volatile("s_waitcnt vmcnt(34)" ::: "memory");
        } else {
            __builtin_amdgcn_sched_barrier(0);
            // last chunk: only stores(c-1):4 may remain in flight
            asm volatile("s_waitcnt vmcnt(4)" ::: "memory");
        }
        __builtin_amdgcn_s_barrier();              // all waves' chunk-c data visible
        __builtin_amdgcn_sched_barrier(0);

        // ---- compute chunk c from buf[c&1] (fits is block-uniform -> no divergence) ----
        const float* lb = sm[c & 1];
        if (fits[c & 1]) {
            const int offL = (lo_d[c & 1] * SH_CAP + lo_h[c & 1]) * SW_CAP + lo_w[c & 1];
#pragma unroll
            for (int k = 0; k < VPT; ++k) {
                const DimS sd = prep(ld, (float)(D - 1), D - 1);
                const DimS sh = prep(lh, (float)(H - 1), H - 1);
                const DimS sw = prep(lw, (float)(W - 1), W - 1);
                const int idx = (sd.i0 * SH_CAP + sh.i0) * SW_CAP + sw.i0 - offL;
                const float2 v00 = make_float2(lb[idx],                  lb[idx + 1]);
                const float2 v01 = make_float2(lb[idx + SW_CAP],         lb[idx + SW_CAP + 1]);
                const float2 v10 = make_float2(lb[idx + PLANE],          lb[idx + PLANE + 1]);
                const float2 v11 = make_float2(lb[idx + PLANE + SW_CAP], lb[idx + PLANE + SW_CAP + 1]);
                const float r = lerp3(sd, sh, sw, v00, v01, v10, v11);
                __builtin_nontemporal_store(r, obk);
                obk += HW;
                ld += a00; lh += a10; lw += a20;
            }
        } else {
            // fallback: R4-verified global-gather path (identical arithmetic).
            // Its loads are newer than stage(c+1) in the FIFO; compiler-inserted
            // waits for their uses keep the vmcnt bookkeeping conservative-correct.
#pragma unroll
            for (int k = 0; k < VPT; ++k) {
                const DimS sd = prep(ld, (float)(D - 1), D - 1);
                const DimS sh = prep(lh, (float)(H - 1), H - 1);
                const DimS sw = prep(lw, (float)(W - 1), W - 1);
                const float r = trilerp_g(vb, sd, sh, sw);
                __builtin_nontemporal_store(r, obk);
                obk += HW;
                ld += a00; lh += a10; lw += a20;
            }
        }
        __builtin_amdgcn_s_barrier();              // WAR: reads done before stage(c+2)
        __builtin_amdgcn_sched_barrier(0);
    }
}

extern "C" void kernel_launch(void* const* d_in, const int* in_sizes, int n_in,
                              void* d_out, int out_size, void* d_ws, size_t ws_size,
                              hipStream_t stream) {
    const float* vol = (const float*)d_in[0];
    const float* trf = (const float*)d_in[1];
    float* out = (float*)d_out;

    dim3 grid(GXH * GXW, D / (VPT * NC), B);   // (120, 10, 4) = 4800 blocks
    dim3 block(TW, TH, 1);
    st_affine_kernel<<<grid, block, 0, stream>>>(vol, trf, out);
}

// Round 6
// 153.614 us; speedup vs baseline: 1.0411x; 1.0411x over previous
//
#include <hip/hip_runtime.h>

// Batched 3D affine spatial transformer: vol [B=4,160,192,160,1] fp32, trf [4,4,4] fp32.
// R10: R9's intra-block pipeline REGRESSED (58->86us): occupancy 66->40% -- at 8 blk/CU
// the one-shot blocks already overlap each other's drains (inter-block TLP IS the
// pipeline); explicit double-buffer traded that away for nothing. Revert to R8 and cut
// its real residual cost: staging issued 120 scalar 4B global_load_lds per block (30
// vmcnt events/wave). Now: linear slab layout (stride SW_PAD=44, lo_w aligned to 4 so
// global rows are 16B-aligned) staged with ~18-21 global_load_lds_dwordx4 total
// (<=6/wave) -- 6x fewer staging instructions. Out-of-slab slots get real-but-unused
// volume data (addr clamped to V-4); gather unchanged except stride 40->44 (2-way bank
// pattern, free). LDS 21.1KB -> 7 blk/CU (R7/R8: 6->8 blocks bought ~1us, so fine).
constexpr int D = 160, H = 192, W = 160, B = 4;
constexpr int V  = D * H * W;
constexpr int HW = H * W;
constexpr int VPT = 4;                 // output voxels per thread along d
constexpr int TW  = 32, TH = 8;        // output tile in (w,h); block = (32,8)
constexpr int GXW = W / TW;            // 5
constexpr int GXH = H / TH;            // 24
constexpr int SD_CAP = 10, SH_CAP = 12, SW_PAD = 44;   // 44 % 4 == 0 (lane-16B rule)
constexpr int PLANE = SH_CAP * SW_PAD;            // 528 floats
constexpr int LDS_FLOATS = SD_CAP * PLANE;        // 5280 floats = 21120 B -> 7 blk/CU

struct DimS { int i0; float w0; };

// Equivalent to neuron.utils interpn clipping (verified R3):
//   c = clip(loc,0,max); i0 = min((int)c, maxi-1); i1 = i0+1; w0 = (i0+1) - c.
__device__ __forceinline__ DimS prep(float loc, float maxv, int maxi) {
    float c  = __builtin_amdgcn_fmed3f(loc, 0.0f, maxv);   // clamp, 1 VALU
    int  i0  = min((int)c, maxi - 1);
    DimS s;
    s.i0 = i0;
    s.w0 = (float)(i0 + 1) - c;
    return s;
}

__device__ __forceinline__ float lerp3(DimS sd, DimS sh, DimS sw,
                                       float2 v00, float2 v01,
                                       float2 v10, float2 v11) {
    const float pd00 = fmaf(sw.w0, v00.x - v00.y, v00.y);
    const float pd01 = fmaf(sw.w0, v01.x - v01.y, v01.y);
    const float pd10 = fmaf(sw.w0, v10.x - v10.y, v10.y);
    const float pd11 = fmaf(sw.w0, v11.x - v11.y, v11.y);
    const float q0 = fmaf(sh.w0, pd00 - pd01, pd01);
    const float q1 = fmaf(sh.w0, pd10 - pd11, pd11);
    return fmaf(sd.w0, q0 - q1, q1);
}

__device__ __forceinline__ float trilerp_g(const float* __restrict__ vb,
                                           DimS sd, DimS sh, DimS sw) {
    const float* p0 = vb + ((sd.i0 * H + sh.i0) * W + sw.i0);
    float2 v00, v01, v10, v11;
    __builtin_memcpy(&v00, p0,          8);
    __builtin_memcpy(&v01, p0 + W,      8);
    __builtin_memcpy(&v10, p0 + HW,     8);
    __builtin_memcpy(&v11, p0 + HW + W, 8);
    return lerp3(sd, sh, sw, v00, v01, v10, v11);
}

// Async global->LDS, 16B/lane (global_load_lds_dwordx4). LDS dest is wave-uniform
// base + lane*16 (HW rule); source address is per-lane. Inactive lanes do nothing.
__device__ __forceinline__ void gload_lds16(const float* g, float* l) {
    __builtin_amdgcn_global_load_lds(
        (const __attribute__((address_space(1))) void*)g,
        (__attribute__((address_space(3))) void*)l,
        16, 0, 0);
}

__global__ __launch_bounds__(256) void st_affine_kernel(
        const float* __restrict__ vol, const float* __restrict__ trf,
        float* __restrict__ out) {
    __shared__ float sm[LDS_FLOATS];

    const int b  = blockIdx.z;
    const int d0 = blockIdx.y * VPT;
    const int hblk = blockIdx.x / GXW;
    const int wblk = blockIdx.x - hblk * GXW;
    const int w0 = wblk * TW, h0 = hblk * TH;

    const float* __restrict__ A = trf + b * 16;   // wave-uniform -> scalar loads
    const float a00 = A[0], a01 = A[1], a02 = A[2],  a03 = A[3];
    const float a10 = A[4], a11 = A[5], a12 = A[6],  a13 = A[7];
    const float a20 = A[8], a21 = A[9], a22 = A[10], a23 = A[11];

    constexpr float cd = (D - 1) * 0.5f;
    constexpr float ch = (H - 1) * 0.5f;
    constexpr float cw = (W - 1) * 0.5f;

    // ---- input coords at the tile origin (voxel (d0,h0,w0)) ----
    const float md0 = (float)d0 - cd, mh0 = (float)h0 - ch, mw0 = (float)w0 - cw;
    const float od = cd + fmaf(a00, md0, fmaf(a01, mh0, fmaf(a02, mw0, a03)));
    const float oh = ch + fmaf(a10, md0, fmaf(a11, mh0, fmaf(a12, mw0, a13)));
    const float ow = cw + fmaf(a20, md0, fmaf(a21, mh0, fmaf(a22, mw0, a23)));

    // ---- block-uniform input bbox (affine -> extremes at tile corners) ----
    const float Ed = (float)(VPT - 1), Eh = (float)(TH - 1), Ew = (float)(TW - 1);
    const float dn = od + fminf(a00*Ed,0.f) + fminf(a01*Eh,0.f) + fminf(a02*Ew,0.f);
    const float dx = od + fmaxf(a00*Ed,0.f) + fmaxf(a01*Eh,0.f) + fmaxf(a02*Ew,0.f);
    const float hn = oh + fminf(a10*Ed,0.f) + fminf(a11*Eh,0.f) + fminf(a12*Ew,0.f);
    const float hx = oh + fmaxf(a10*Ed,0.f) + fmaxf(a11*Eh,0.f) + fmaxf(a12*Ew,0.f);
    const float wn = ow + fminf(a20*Ed,0.f) + fminf(a21*Eh,0.f) + fminf(a22*Ew,0.f);
    const float wx = ow + fmaxf(a20*Ed,0.f) + fmaxf(a21*Eh,0.f) + fmaxf(a22*Ew,0.f);

    // lo = min i0 over tile, hi = max i1 over tile ((int)clip is monotone in loc)
    const int lo_d = min((int)__builtin_amdgcn_fmed3f(dn, 0.f, (float)(D-1)), D - 2);
    const int hi_d = min((int)__builtin_amdgcn_fmed3f(dx, 0.f, (float)(D-1)), D - 2) + 1;
    const int lo_h = min((int)__builtin_amdgcn_fmed3f(hn, 0.f, (float)(H-1)), H - 2);
    const int hi_h = min((int)__builtin_amdgcn_fmed3f(hx, 0.f, (float)(H-1)), H - 2) + 1;
    const int lo_w = min((int)__builtin_amdgcn_fmed3f(wn, 0.f, (float)(W-1)), W - 2);
    const int hi_w = min((int)__builtin_amdgcn_fmed3f(wx, 0.f, (float)(W-1)), W - 2) + 1;
    const int lo_w_al = lo_w & ~3;                 // 16B-aligned slab origin in w
    const int SDn = hi_d - lo_d + 1;
    const int SHn = hi_h - lo_h + 1;
    const int SWa = hi_w - lo_w_al + 1;            // aligned-origin w extent

    // ---- per-voxel coords for k=0; voxel k adds k*column0(A) ----
    const float fy = (float)threadIdx.y, fx = (float)threadIdx.x;
    float ld = fmaf(a01, fy, fmaf(a02, fx, od));
    float lh = fmaf(a11, fy, fmaf(a12, fx, oh));
    float lw = fmaf(a21, fy, fmaf(a22, fx, ow));

    const float* __restrict__ vb = vol + (size_t)b * V;
    // Block-uniform store base (SGPR) + per-thread 32-bit offset -> saddr stores.
    float* __restrict__ ob = out + (size_t)b * V + (size_t)d0 * HW;
    const int oofs = (h0 + threadIdx.y) * W + w0 + threadIdx.x;

    // idx+1 needs col <= SW_PAD-1, idx+SW_PAD needs row <= SH_CAP-1, +PLANE needs
    // plane <= SD_CAP-1  =>  fit iff SDn<=SD_CAP && SHn<=SH_CAP && SWa<=SW_PAD.
    if (SDn <= SD_CAP && SHn <= SH_CAP && SWa <= SW_PAD) {
        // ---- LDS path: linear 16B/lane slab staging, then LDS gather ----
        const int tid  = threadIdx.y * TW + threadIdx.x;
        const int wv   = tid >> 6;          // wave id 0..3
        const int lane = tid & 63;
        const int base_off = (lo_d * H + lo_h) * W + lo_w_al;   // 16B-aligned
        const int lim = SDn * PLANE;        // stage only the z-planes we need
        // Instruction i covers slab floats [i*256, i*256+256); wave w takes i=w,w+4,...
        // ceil(lim/256) <= ceil(5280/256) = 21 instructions total, <=6 per wave.
        for (int t = 0; t < 6; ++t) {
            const int i  = wv + t * 4;
            const int Lb = i * 256;
            if (Lb >= lim) break;           // wave-uniform exit
            const int L = Lb + lane * 4;
            if (L < lim) {                  // partial last instruction
                const int z = L / PLANE;    // magic-mul division (constants)
                const int r = L - z * PLANE;
                const int y = r / SW_PAD;
                const int x = r - y * SW_PAD;
                // 44%4==0 => each lane's 4 floats stay inside one slab row.
                // Rows y>=SHn / cols beyond hi_w load real-but-unused volume data;
                // clamp to V-4 keeps every access inside this batch's volume.
                const int off = min(base_off + (z * H + y) * W + x, V - 4);
                gload_lds16(vb + off, sm + Lb);
            }
        }
        __syncthreads();                    // drains vmcnt before s_barrier

        const int offL = (lo_d * SH_CAP + lo_h) * SW_PAD + lo_w_al;
#pragma unroll
        for (int k = 0; k < VPT; ++k) {
            const DimS sd = prep(ld, (float)(D - 1), D - 1);
            const DimS sh = prep(lh, (float)(H - 1), H - 1);
            const DimS sw = prep(lw, (float)(W - 1), W - 1);
            const int idx = (sd.i0 * SH_CAP + sh.i0) * SW_PAD + sw.i0 - offL;
            const float2 v00 = make_float2(sm[idx],                  sm[idx + 1]);
            const float2 v01 = make_float2(sm[idx + SW_PAD],         sm[idx + SW_PAD + 1]);
            const float2 v10 = make_float2(sm[idx + PLANE],          sm[idx + PLANE + 1]);
            const float2 v11 = make_float2(sm[idx + PLANE + SW_PAD], sm[idx + PLANE + SW_PAD + 1]);
            const float r = lerp3(sd, sh, sw, v00, v01, v10, v11);
            __builtin_nontemporal_store(r, ob + oofs + k * HW);
            ld += a00; lh += a10; lw += a20;
        }
    } else {
        // ---- fallback: R4-verified global-gather path (identical arithmetic) ----
#pragma unroll
        for (int k = 0; k < VPT; ++k) {
            const DimS sd = prep(ld, (float)(D - 1), D - 1);
            const DimS sh = prep(lh, (float)(H - 1), H - 1);
            const DimS sw = prep(lw, (float)(W - 1), W - 1);
            const float r = trilerp_g(vb, sd, sh, sw);
            __builtin_nontemporal_store(r, ob + oofs + k * HW);
            ld += a00; lh += a10; lw += a20;
        }
    }
}

extern "C" void kernel_launch(void* const* d_in, const int* in_sizes, int n_in,
                              void* d_out, int out_size, void* d_ws, size_t ws_size,
                              hipStream_t stream) {
    const float* vol = (const float*)d_in[0];
    const float* trf = (const float*)d_in[1];
    float* out = (float*)d_out;

    dim3 grid(GXH * GXW, D / VPT, B);   // (120, 40, 4)
    dim3 block(TW, TH, 1);
    st_affine_kernel<<<grid, block, 0, stream>>>(vol, trf, out);
}

// Round 7
// 148.413 us; speedup vs baseline: 1.0775x; 1.0350x over previous
//
#include <hip/hip_runtime.h>

// Batched 3D affine spatial transformer: vol [B=4,160,192,160,1] fp32, trf [4,4,4] fp32.
// R11: R10 (16B/lane linear staging) won 58.4->55.4us but its padding rows fetched NEW
// addresses: FETCH 85.8->130.8MB (+45MB HBM waste, rows y>=SHn / box padding). Pipe
// model now: LDS-read ~33us (incl 10us conflicts), HBM ~34us (waste-inflated) -> both
// ~60% loaded, imperfectly overlapped. Two orthogonal fixes:
//  (a) clamp padded staging rows' SOURCE addr to min(y,SHn-1): dup rows re-fetch
//      just-fetched lines -> L1/L2 hits, ~zero HBM; their LDS slots are never read.
//  (b) corner pairs via 8B memcpy from LDS -> ds_read2_b32/b64 (32 -> ~16 DS instrs
//      per thread; 44B/cyc -> ~70B/cyc effective LDS throughput per m134).
constexpr int D = 160, H = 192, W = 160, B = 4;
constexpr int V  = D * H * W;
constexpr int HW = H * W;
constexpr int VPT = 4;                 // output voxels per thread along d
constexpr int TW  = 32, TH = 8;        // output tile in (w,h); block = (32,8)
constexpr int GXW = W / TW;            // 5
constexpr int GXH = H / TH;            // 24
constexpr int SD_CAP = 10, SH_CAP = 12, SW_PAD = 44;   // 44 % 4 == 0 (lane-16B rule)
constexpr int PLANE = SH_CAP * SW_PAD;            // 528 floats
constexpr int LDS_FLOATS = SD_CAP * PLANE;        // 5280 floats = 21120 B -> 7 blk/CU

struct DimS { int i0; float w0; };

// Equivalent to neuron.utils interpn clipping (verified R3):
//   c = clip(loc,0,max); i0 = min((int)c, maxi-1); i1 = i0+1; w0 = (i0+1) - c.
__device__ __forceinline__ DimS prep(float loc, float maxv, int maxi) {
    float c  = __builtin_amdgcn_fmed3f(loc, 0.0f, maxv);   // clamp, 1 VALU
    int  i0  = min((int)c, maxi - 1);
    DimS s;
    s.i0 = i0;
    s.w0 = (float)(i0 + 1) - c;
    return s;
}

__device__ __forceinline__ float lerp3(DimS sd, DimS sh, DimS sw,
                                       float2 v00, float2 v01,
                                       float2 v10, float2 v11) {
    const float pd00 = fmaf(sw.w0, v00.x - v00.y, v00.y);
    const float pd01 = fmaf(sw.w0, v01.x - v01.y, v01.y);
    const float pd10 = fmaf(sw.w0, v10.x - v10.y, v10.y);
    const float pd11 = fmaf(sw.w0, v11.x - v11.y, v11.y);
    const float q0 = fmaf(sh.w0, pd00 - pd01, pd01);
    const float q1 = fmaf(sh.w0, pd10 - pd11, pd11);
    return fmaf(sd.w0, q0 - q1, q1);
}

__device__ __forceinline__ float2 ld2_lds(const float* l) {   // 4B-aligned 8B LDS read
    float2 v;
    __builtin_memcpy(&v, l, 8);        // -> ds_read2_b32 (or b64 when provably aligned)
    return v;
}

__device__ __forceinline__ float trilerp_g(const float* __restrict__ vb,
                                           DimS sd, DimS sh, DimS sw) {
    const float* p0 = vb + ((sd.i0 * H + sh.i0) * W + sw.i0);
    float2 v00, v01, v10, v11;
    __builtin_memcpy(&v00, p0,          8);
    __builtin_memcpy(&v01, p0 + W,      8);
    __builtin_memcpy(&v10, p0 + HW,     8);
    __builtin_memcpy(&v11, p0 + HW + W, 8);
    return lerp3(sd, sh, sw, v00, v01, v10, v11);
}

// Async global->LDS, 16B/lane (global_load_lds_dwordx4). LDS dest is wave-uniform
// base + lane*16 (HW rule); source address is per-lane. Inactive lanes do nothing.
__device__ __forceinline__ void gload_lds16(const float* g, float* l) {
    __builtin_amdgcn_global_load_lds(
        (const __attribute__((address_space(1))) void*)g,
        (__attribute__((address_space(3))) void*)l,
        16, 0, 0);
}

__global__ __launch_bounds__(256) void st_affine_kernel(
        const float* __restrict__ vol, const float* __restrict__ trf,
        float* __restrict__ out) {
    __shared__ float sm[LDS_FLOATS];

    const int b  = blockIdx.z;
    const int d0 = blockIdx.y * VPT;
    const int hblk = blockIdx.x / GXW;
    const int wblk = blockIdx.x - hblk * GXW;
    const int w0 = wblk * TW, h0 = hblk * TH;

    const float* __restrict__ A = trf + b * 16;   // wave-uniform -> scalar loads
    const float a00 = A[0], a01 = A[1], a02 = A[2],  a03 = A[3];
    const float a10 = A[4], a11 = A[5], a12 = A[6],  a13 = A[7];
    const float a20 = A[8], a21 = A[9], a22 = A[10], a23 = A[11];

    constexpr float cd = (D - 1) * 0.5f;
    constexpr float ch = (H - 1) * 0.5f;
    constexpr float cw = (W - 1) * 0.5f;

    // ---- input coords at the tile origin (voxel (d0,h0,w0)) ----
    const float md0 = (float)d0 - cd, mh0 = (float)h0 - ch, mw0 = (float)w0 - cw;
    const float od = cd + fmaf(a00, md0, fmaf(a01, mh0, fmaf(a02, mw0, a03)));
    const float oh = ch + fmaf(a10, md0, fmaf(a11, mh0, fmaf(a12, mw0, a13)));
    const float ow = cw + fmaf(a20, md0, fmaf(a21, mh0, fmaf(a22, mw0, a23)));

    // ---- block-uniform input bbox (affine -> extremes at tile corners) ----
    const float Ed = (float)(VPT - 1), Eh = (float)(TH - 1), Ew = (float)(TW - 1);
    const float dn = od + fminf(a00*Ed,0.f) + fminf(a01*Eh,0.f) + fminf(a02*Ew,0.f);
    const float dx = od + fmaxf(a00*Ed,0.f) + fmaxf(a01*Eh,0.f) + fmaxf(a02*Ew,0.f);
    const float hn = oh + fminf(a10*Ed,0.f) + fminf(a11*Eh,0.f) + fminf(a12*Ew,0.f);
    const float hx = oh + fmaxf(a10*Ed,0.f) + fmaxf(a11*Eh,0.f) + fmaxf(a12*Ew,0.f);
    const float wn = ow + fminf(a20*Ed,0.f) + fminf(a21*Eh,0.f) + fminf(a22*Ew,0.f);
    const float wx = ow + fmaxf(a20*Ed,0.f) + fmaxf(a21*Eh,0.f) + fmaxf(a22*Ew,0.f);

    // lo = min i0 over tile, hi = max i1 over tile ((int)clip is monotone in loc)
    const int lo_d = min((int)__builtin_amdgcn_fmed3f(dn, 0.f, (float)(D-1)), D - 2);
    const int hi_d = min((int)__builtin_amdgcn_fmed3f(dx, 0.f, (float)(D-1)), D - 2) + 1;
    const int lo_h = min((int)__builtin_amdgcn_fmed3f(hn, 0.f, (float)(H-1)), H - 2);
    const int hi_h = min((int)__builtin_amdgcn_fmed3f(hx, 0.f, (float)(H-1)), H - 2) + 1;
    const int lo_w = min((int)__builtin_amdgcn_fmed3f(wn, 0.f, (float)(W-1)), W - 2);
    const int hi_w = min((int)__builtin_amdgcn_fmed3f(wx, 0.f, (float)(W-1)), W - 2) + 1;
    const int lo_w_al = lo_w & ~3;                 // 16B-aligned slab origin in w
    const int SDn = hi_d - lo_d + 1;
    const int SHn = hi_h - lo_h + 1;
    const int SWa = hi_w - lo_w_al + 1;            // aligned-origin w extent

    // ---- per-voxel coords for k=0; voxel k adds k*column0(A) ----
    const float fy = (float)threadIdx.y, fx = (float)threadIdx.x;
    float ld = fmaf(a01, fy, fmaf(a02, fx, od));
    float lh = fmaf(a11, fy, fmaf(a12, fx, oh));
    float lw = fmaf(a21, fy, fmaf(a22, fx, ow));

    const float* __restrict__ vb = vol + (size_t)b * V;
    // Block-uniform store base (SGPR) + per-thread 32-bit offset -> saddr stores.
    float* __restrict__ ob = out + (size_t)b * V + (size_t)d0 * HW;
    const int oofs = (h0 + threadIdx.y) * W + w0 + threadIdx.x;

    // idx+1 needs col <= SW_PAD-1, idx+SW_PAD needs row <= SH_CAP-1, +PLANE needs
    // plane <= SD_CAP-1  =>  fit iff SDn<=SD_CAP && SHn<=SH_CAP && SWa<=SW_PAD.
    if (SDn <= SD_CAP && SHn <= SH_CAP && SWa <= SW_PAD) {
        // ---- LDS path: linear 16B/lane slab staging, then LDS gather ----
        const int tid  = threadIdx.y * TW + threadIdx.x;
        const int wv   = tid >> 6;          // wave id 0..3
        const int lane = tid & 63;
        const int base_off = (lo_d * H + lo_h) * W + lo_w_al;   // 16B-aligned
        const int lim = SDn * PLANE;        // stage only the z-planes we need
        // Instruction i covers slab floats [i*256, i*256+256); wave w takes i=w,w+4,...
        // ceil(lim/256) <= ceil(5280/256) = 21 instructions total, <=6 per wave.
        for (int t = 0; t < 6; ++t) {
            const int i  = wv + t * 4;
            const int Lb = i * 256;
            if (Lb >= lim) break;           // wave-uniform exit
            const int L = Lb + lane * 4;
            if (L < lim) {                  // partial last instruction
                const int z = L / PLANE;    // magic-mul division (constants)
                const int r = L - z * PLANE;
                const int y = r / SW_PAD;
                const int x = r - y * SW_PAD;
                // 44%4==0 => each lane's 4 floats stay inside one slab row.
                // Rows y>=SHn would fetch NEW addresses (R10: +45MB HBM) -> clamp the
                // SOURCE to row SHn-1: dup loads hit L1/L2 (just-fetched lines), and
                // those LDS slots are never read (sh.i0+1 <= SHn-1). Source addr of
                // global_load_lds is per-lane, so per-lane clamp is legal.
                const int ys  = min(y, SHn - 1);
                const int off = min(base_off + (z * H + ys) * W + x, V - 4);
                gload_lds16(vb + off, sm + Lb);
            }
        }
        __syncthreads();                    // drains vmcnt before s_barrier

        const int offL = (lo_d * SH_CAP + lo_h) * SW_PAD + lo_w_al;
#pragma unroll
        for (int k = 0; k < VPT; ++k) {
            const DimS sd = prep(ld, (float)(D - 1), D - 1);
            const DimS sh = prep(lh, (float)(H - 1), H - 1);
            const DimS sw = prep(lw, (float)(W - 1), W - 1);
            const int idx = (sd.i0 * SH_CAP + sh.i0) * SW_PAD + sw.i0 - offL;
            const float* p = sm + idx;
            const float2 v00 = ld2_lds(p);
            const float2 v01 = ld2_lds(p + SW_PAD);
            const float2 v10 = ld2_lds(p + PLANE);
            const float2 v11 = ld2_lds(p + PLANE + SW_PAD);
            const float r = lerp3(sd, sh, sw, v00, v01, v10, v11);
            __builtin_nontemporal_store(r, ob + oofs + k * HW);
            ld += a00; lh += a10; lw += a20;
        }
    } else {
        // ---- fallback: R4-verified global-gather path (identical arithmetic) ----
#pragma unroll
        for (int k = 0; k < VPT; ++k) {
            const DimS sd = prep(ld, (float)(D - 1), D - 1);
            const DimS sh = prep(lh, (float)(H - 1), H - 1);
            const DimS sw = prep(lw, (float)(W - 1), W - 1);
            const float r = trilerp_g(vb, sd, sh, sw);
            __builtin_nontemporal_store(r, ob + oofs + k * HW);
            ld += a00; lh += a10; lw += a20;
        }
    }
}

extern "C" void kernel_launch(void* const* d_in, const int* in_sizes, int n_in,
                              void* d_out, int out_size, void* d_ws, size_t ws_size,
                              hipStream_t stream) {
    const float* vol = (const float*)d_in[0];
    const float* trf = (const float*)d_in[1];
    float* out = (float*)d_out;

    dim3 grid(GXH * GXW, D / VPT, B);   // (120, 40, 4)
    dim3 block(TW, TH, 1);
    st_affine_kernel<<<grid, block, 0, stream>>>(vol, trf, out);
}